// Round 3
// baseline (750.027 us; speedup 1.0000x reference)
//
#include <hip/hip_runtime.h>
#include <hip/hip_bf16.h>
#include <cmath>

typedef __bf16 bf16_t;
typedef __bf16 bf16x8 __attribute__((ext_vector_type(8)));
typedef __bf16 bf16x4 __attribute__((ext_vector_type(4)));
typedef float f32x4 __attribute__((ext_vector_type(4)));

#define LATENT 1024
#define HEADS 16
#define HD 64
#define TX 4096
#define TXF 256
#define SCALE_ATTN 0.125f

static __device__ __forceinline__ float b2f(bf16_t b) { return (float)b; }
static __device__ __forceinline__ bf16_t f2b(float f) { return (bf16_t)f; }

// ---------------- f32 -> bf16 convert (vectorized, grid-stride) ----------
__global__ __launch_bounds__(256) void cvt_k(const float* __restrict__ in,
                                             bf16_t* __restrict__ out, long n4) {
    long i = (long)blockIdx.x * 256 + threadIdx.x;
    long stride = (long)gridDim.x * 256;
    for (; i < n4; i += stride) {
        float4 v = ((const float4*)in)[i];
        bf16x4 o;
        o[0] = f2b(v.x); o[1] = f2b(v.y); o[2] = f2b(v.z); o[3] = f2b(v.w);
        *(bf16x4*)&out[i * 4] = o;
    }
}

// ------------- transpose+convert: in f32 [R][C] -> out bf16 [C][R] -------
__global__ __launch_bounds__(256) void tr_k(const float* __restrict__ in,
                                            bf16_t* __restrict__ out,
                                            int R, int C) {
    __shared__ float t[32][33];
    int bx = blockIdx.x, by = blockIdx.y;
    int x = threadIdx.x & 31, y0 = threadIdx.x >> 5;  // 32 x 8
    for (int i = 0; i < 32; i += 8)
        t[y0 + i][x] = in[(long)(by * 32 + y0 + i) * C + bx * 32 + x];
    __syncthreads();
    for (int i = 0; i < 32; i += 8)
        out[(long)(bx * 32 + y0 + i) * R + by * 32 + x] = f2b(t[x][y0 + i]);
}

// ---------------- GEMM: C[M,N] = A[M,K] @ Bt[N,K]^T + bias(f32) ----------
// EPI: 0 = bf16 store, 2 = exact-GELU -> bf16,
//      3 = + resb16(bf16) + resf32(f32) -> F32 store (final output)
template <int EPI>
__global__ __launch_bounds__(256, 2) void gemm_k(
    const bf16_t* __restrict__ A, const bf16_t* __restrict__ Bt,
    const float* __restrict__ bias, void* __restrict__ C,
    const bf16_t* __restrict__ resb16, const float* __restrict__ resf32,
    int M, int N, int K) {
    // 128x128 tile, BK=32, 4 waves 2x2, each wave 4x4 of 16x16x32 MFMA.
    // LDS chunk swizzle chunk' = chunk ^ ((row>>1)&3): 16B-aligned, <=2-way.
    __shared__ __align__(16) bf16_t As[128 * 32];
    __shared__ __align__(16) bf16_t Bs[128 * 32];
    int tid = threadIdx.x;
    int lane = tid & 63, wid = tid >> 6;
    int quad = lane >> 4, l16 = lane & 15;
    int wm = wid >> 1, wn = wid & 1;
    int srow = tid >> 2, schk = tid & 3;
    int swz = schk ^ ((srow >> 1) & 3);  // same for srow+64

    f32x4 acc[4][4] = {};
    long bm = blockIdx.x, bn = blockIdx.y;
    const bf16_t* Ab = A + (bm * 128 + srow) * (long)K + schk * 8;
    const bf16_t* Bb = Bt + (bn * 128 + srow) * (long)K + schk * 8;

    for (int k0 = 0; k0 < K; k0 += 32) {
        uint4 va0 = *(const uint4*)(Ab + k0);
        uint4 va1 = *(const uint4*)(Ab + 64 * (long)K + k0);
        uint4 vb0 = *(const uint4*)(Bb + k0);
        uint4 vb1 = *(const uint4*)(Bb + 64 * (long)K + k0);
        __syncthreads();
        *(uint4*)&As[srow * 32 + swz * 8] = va0;
        *(uint4*)&As[(srow + 64) * 32 + swz * 8] = va1;
        *(uint4*)&Bs[srow * 32 + swz * 8] = vb0;
        *(uint4*)&Bs[(srow + 64) * 32 + swz * 8] = vb1;
        __syncthreads();
        bf16x8 af[4], bfr[4];
#pragma unroll
        for (int mi = 0; mi < 4; mi++) {
            int r = wm * 64 + mi * 16 + l16;
            af[mi] = *(const bf16x8*)&As[r * 32 + (quad ^ ((r >> 1) & 3)) * 8];
        }
#pragma unroll
        for (int ni = 0; ni < 4; ni++) {
            int r = wn * 64 + ni * 16 + l16;
            bfr[ni] = *(const bf16x8*)&Bs[r * 32 + (quad ^ ((r >> 1) & 3)) * 8];
        }
#pragma unroll
        for (int mi = 0; mi < 4; mi++)
#pragma unroll
            for (int ni = 0; ni < 4; ni++)
                acc[mi][ni] = __builtin_amdgcn_mfma_f32_16x16x32_bf16(
                    af[mi], bfr[ni], acc[mi][ni], 0, 0, 0);
    }

    // C/D layout: col = lane&15, row = quad*4 + reg (verified m89/m91)
    int colb = (int)bn * 128 + wn * 64;
    float bvv[4];
#pragma unroll
    for (int ni = 0; ni < 4; ni++) bvv[ni] = bias[colb + ni * 16 + l16];
#pragma unroll
    for (int mi = 0; mi < 4; mi++) {
        long grow = bm * 128 + wm * 64 + mi * 16 + quad * 4;
#pragma unroll
        for (int r = 0; r < 4; r++) {
            long ro = (grow + r) * (long)N;
#pragma unroll
            for (int ni = 0; ni < 4; ni++) {
                long idx = ro + colb + ni * 16 + l16;
                float v = acc[mi][ni][r] + bvv[ni];
                if (EPI == 0) {
                    ((bf16_t*)C)[idx] = f2b(v);
                } else if (EPI == 2) {
                    ((bf16_t*)C)[idx] =
                        f2b(0.5f * v * (1.0f + erff(v * 0.70710678118f)));
                } else {
                    // final: ffn + attn_out(bf16) + x(f32), stored f32
                    ((float*)C)[idx] = v + b2f(resb16[idx]) + resf32[idx];
                }
            }
        }
    }
}

// ---------------- fused attention (all-bf16 internal buffers) ------------
// Q[16384,1024], K/V[1024,1024] laid out (b*T + t, h*64 + d).
// Block: 64 q-rows of one (b,h). LDS 64KB: Ks swizzled [256][64] (later
// aliased by Ps [64][256]); Vt transposed swizzled [64 d][256 kk].
__global__ __launch_bounds__(256, 2) void attn_k(const bf16_t* __restrict__ Q,
                                                 const bf16_t* __restrict__ Kb,
                                                 const bf16_t* __restrict__ Vb,
                                                 bf16_t* __restrict__ Ob) {
    __shared__ __align__(16) bf16_t SM[32768];
    bf16_t* Ks = SM;
    bf16_t* Vt = SM + 16384;
    int tid = threadIdx.x;
    int lane = tid & 63, w = tid >> 6;
    int quad = lane >> 4, l16 = lane & 15;
    int qt = blockIdx.x & 63;
    int bh = blockIdx.x >> 6;
    int b = bh >> 4, h = bh & 15;

    {  // stage K (natural, swizzled) + V (transposed, swizzled); row = tid
        const uint4* ks = (const uint4*)(Kb + ((long)(b * TXF + tid) * LATENT + h * HD));
#pragma unroll
        for (int cc = 0; cc < 8; cc++)
            *(uint4*)&Ks[tid * 64 + ((cc ^ (tid & 7)) * 8)] = ks[cc];
        const uint4* vs = (const uint4*)(Vb + ((long)(b * TXF + tid) * LATENT + h * HD));
#pragma unroll
        for (int cc = 0; cc < 8; cc++) {
            uint4 v = vs[cc];
            const bf16_t* e = (const bf16_t*)&v;
#pragma unroll
            for (int j = 0; j < 8; j++) {
                int d = cc * 8 + j;
                Vt[d * 256 + (((tid >> 3) ^ (d & 7)) * 8) + (tid & 7)] = e[j];
            }
        }
    }
    // Q A-fragments from global (read-once): A[m=lane&15][k=quad*8+j]
    long qrow = (long)(b * TX + qt * 64 + w * 16 + l16) * LATENT + h * HD;
    bf16x8 aq0 = *(const bf16x8*)(Q + qrow + quad * 8);
    bf16x8 aq1 = *(const bf16x8*)(Q + qrow + 32 + quad * 8);
    __syncthreads();

    // scores: wave w owns q-rows [w*16, w*16+16), all 256 cols
    f32x4 sacc[16] = {};
#pragma unroll
    for (int ni = 0; ni < 16; ni++) {
        int kr = ni * 16 + l16;
        bf16x8 b0 = *(const bf16x8*)&Ks[kr * 64 + ((quad ^ (kr & 7)) * 8)];
        bf16x8 b1 = *(const bf16x8*)&Ks[kr * 64 + (((4 + quad) ^ (kr & 7)) * 8)];
        sacc[ni] = __builtin_amdgcn_mfma_f32_16x16x32_bf16(aq0, b0, sacc[ni], 0, 0, 0);
        sacc[ni] = __builtin_amdgcn_mfma_f32_16x16x32_bf16(aq1, b1, sacc[ni], 0, 0, 0);
    }
    // softmax per row (row = quad*4 + r); 16-lane butterfly stays in quad
#pragma unroll
    for (int r = 0; r < 4; r++) {
        float m = -3e38f;
#pragma unroll
        for (int ni = 0; ni < 16; ni++) m = fmaxf(m, sacc[ni][r]);
#pragma unroll
        for (int off = 1; off < 16; off <<= 1) m = fmaxf(m, __shfl_xor(m, off, 64));
        float s = 0.f;
#pragma unroll
        for (int ni = 0; ni < 16; ni++) {
            float p = __expf((sacc[ni][r] - m) * SCALE_ATTN);
            sacc[ni][r] = p;
            s += p;
        }
#pragma unroll
        for (int off = 1; off < 16; off <<= 1) s += __shfl_xor(s, off, 64);
        float inv = 1.0f / s;
#pragma unroll
        for (int ni = 0; ni < 16; ni++) sacc[ni][r] *= inv;
    }
    __syncthreads();  // all waves done reading Ks before Ps overwrites it

    bf16_t* Ps = SM;  // alias over Ks
#pragma unroll
    for (int r = 0; r < 4; r++) {
        int row = w * 16 + quad * 4 + r;
#pragma unroll
        for (int ni = 0; ni < 16; ni++) {
            int col = ni * 16 + l16;
            Ps[row * 256 + (((col >> 3) ^ (row & 7)) * 8) + (col & 7)] =
                f2b(sacc[ni][r]);
        }
    }
    __syncthreads();

    // PV: O[64 q][64 d]; wave w rows [w*16, w*16+16)
    f32x4 oacc[4] = {};
#pragma unroll
    for (int s = 0; s < 8; s++) {
        int prow = w * 16 + l16;
        bf16x8 ap = *(const bf16x8*)&Ps[prow * 256 + (((s * 4 + quad) ^ (prow & 7)) * 8)];
#pragma unroll
        for (int ni = 0; ni < 4; ni++) {
            int vr = ni * 16 + l16;
            bf16x8 bv = *(const bf16x8*)&Vt[vr * 256 + (((s * 4 + quad) ^ (vr & 7)) * 8)];
            oacc[ni] = __builtin_amdgcn_mfma_f32_16x16x32_bf16(ap, bv, oacc[ni], 0, 0, 0);
        }
    }
#pragma unroll
    for (int r = 0; r < 4; r++) {
        long orow = (long)(b * TX + qt * 64 + w * 16 + quad * 4 + r) * LATENT + h * HD;
#pragma unroll
        for (int ni = 0; ni < 4; ni++)
            Ob[orow + ni * 16 + l16] = f2b(oacc[ni][r]);
    }
}

// ------- LayerNorm: bf16 in, f32 gamma/beta (raw inputs), bf16 out -------
__global__ __launch_bounds__(256) void ln_k(const bf16_t* __restrict__ O,
                                            const float* __restrict__ g,
                                            const float* __restrict__ bb,
                                            bf16_t* __restrict__ H) {
    long row = blockIdx.x;
    int c = threadIdx.x * 4;
    bf16x4 v = *(const bf16x4*)(O + row * LATENT + c);
    float vv[4] = {b2f(v[0]), b2f(v[1]), b2f(v[2]), b2f(v[3])};
    float s = vv[0] + vv[1] + vv[2] + vv[3];
    float s2 = vv[0] * vv[0] + vv[1] * vv[1] + vv[2] * vv[2] + vv[3] * vv[3];
#pragma unroll
    for (int off = 1; off < 64; off <<= 1) {
        s += __shfl_xor(s, off, 64);
        s2 += __shfl_xor(s2, off, 64);
    }
    __shared__ float red[8];
    int lane = threadIdx.x & 63, w = threadIdx.x >> 6;
    if (lane == 0) { red[w] = s; red[w + 4] = s2; }
    __syncthreads();
    s = red[0] + red[1] + red[2] + red[3];
    s2 = red[4] + red[5] + red[6] + red[7];
    float mu = s * (1.0f / 1024.0f);
    float var = s2 * (1.0f / 1024.0f) - mu * mu;
    float rstd = rsqrtf(var + 1e-5f);
    bf16_t* out = H + row * LATENT + c;
#pragma unroll
    for (int j = 0; j < 4; j++)
        out[j] = f2b((vv[j] - mu) * rstd * g[c + j] + bb[c + j]);
}

// ---------------- launch ----------------
extern "C" void kernel_launch(void* const* d_in, const int* in_sizes, int n_in,
                              void* d_out, int out_size, void* d_ws,
                              size_t ws_size, hipStream_t stream) {
    // Inputs are FLOAT32; output buffer is FLOAT32 (reference output dtype).
    const float* x = (const float*)d_in[0];
    const float* xf = (const float*)d_in[1];
    const float* Wq = (const float*)d_in[2];
    const float* bq = (const float*)d_in[3];
    const float* Wk = (const float*)d_in[4];
    const float* bk = (const float*)d_in[5];
    const float* Wv = (const float*)d_in[6];
    const float* bv = (const float*)d_in[7];
    const float* Wo = (const float*)d_in[8];
    const float* bo = (const float*)d_in[9];
    const float* lng = (const float*)d_in[10];
    const float* lnb = (const float*)d_in[11];
    const float* W1 = (const float*)d_in[12];
    const float* b1 = (const float*)d_in[13];
    const float* W2 = (const float*)d_in[14];
    const float* b2 = (const float*)d_in[15];

    char* ws = (char*)d_ws;
    size_t off = 0;
    auto alloc = [&](size_t bytes) {
        void* p = ws + off;
        off += (bytes + 255) & ~(size_t)255;
        return p;
    };
    // persistent region (~87 MB)
    bf16_t* WqT = (bf16_t*)alloc((size_t)1024 * 1024 * 2);
    bf16_t* WkT = (bf16_t*)alloc((size_t)1024 * 768 * 2);
    bf16_t* WvT = (bf16_t*)alloc((size_t)1024 * 768 * 2);
    bf16_t* WoT = (bf16_t*)alloc((size_t)1024 * 1024 * 2);
    bf16_t* W1T = (bf16_t*)alloc((size_t)4096 * 1024 * 2);
    bf16_t* W2T = (bf16_t*)alloc((size_t)1024 * 4096 * 2);
    bf16_t* Obuf = (bf16_t*)alloc((size_t)16384 * 1024 * 2);  // attn proj out
    bf16_t* Hbuf = (bf16_t*)alloc((size_t)16384 * 1024 * 2);  // LN out
    // transient region (dead before FFN) — H1 aliases it (total ~215 MB)
    size_t transient0 = off;
    bf16_t* xc = (bf16_t*)alloc((size_t)16384 * 1024 * 2);
    bf16_t* xfc = (bf16_t*)alloc((size_t)1024 * 768 * 2);
    bf16_t* Qbuf = (bf16_t*)alloc((size_t)16384 * 1024 * 2);
    bf16_t* Kbuf = (bf16_t*)alloc((size_t)1024 * 1024 * 2);
    bf16_t* Vbuf = (bf16_t*)alloc((size_t)1024 * 1024 * 2);
    bf16_t* Abuf = (bf16_t*)alloc((size_t)16384 * 1024 * 2);
    bf16_t* H1 = (bf16_t*)(ws + transient0);  // 128 MB over dead transients

    dim3 blk(256);
    // input converts f32 -> bf16
    cvt_k<<<dim3(4096), blk, 0, stream>>>(x, xc, (long)16384 * 1024 / 4);
    cvt_k<<<dim3(768), blk, 0, stream>>>(xf, xfc, (long)1024 * 768 / 4);
    // weight transposes (+convert): grid (C/32, R/32)
    tr_k<<<dim3(32, 32), blk, 0, stream>>>(Wq, WqT, 1024, 1024);
    tr_k<<<dim3(32, 24), blk, 0, stream>>>(Wk, WkT, 768, 1024);
    tr_k<<<dim3(32, 24), blk, 0, stream>>>(Wv, WvT, 768, 1024);
    tr_k<<<dim3(32, 32), blk, 0, stream>>>(Wo, WoT, 1024, 1024);
    tr_k<<<dim3(128, 32), blk, 0, stream>>>(W1, W1T, 1024, 4096);
    tr_k<<<dim3(32, 128), blk, 0, stream>>>(W2, W2T, 4096, 1024);

    // projections
    gemm_k<0><<<dim3(128, 8), blk, 0, stream>>>(xc, WqT, bq, Qbuf, nullptr, nullptr, 16384, 1024, 1024);
    gemm_k<0><<<dim3(8, 8), blk, 0, stream>>>(xfc, WkT, bk, Kbuf, nullptr, nullptr, 1024, 1024, 768);
    gemm_k<0><<<dim3(8, 8), blk, 0, stream>>>(xfc, WvT, bv, Vbuf, nullptr, nullptr, 1024, 1024, 768);
    // attention
    attn_k<<<dim3(4096), blk, 0, stream>>>(Qbuf, Kbuf, Vbuf, Abuf);
    // output projection
    gemm_k<0><<<dim3(128, 8), blk, 0, stream>>>(Abuf, WoT, bo, Obuf, nullptr, nullptr, 16384, 1024, 1024);
    // layernorm
    ln_k<<<dim3(16384), blk, 0, stream>>>(Obuf, lng, lnb, Hbuf);
    // FFN
    gemm_k<2><<<dim3(128, 32), blk, 0, stream>>>(Hbuf, W1T, b1, H1, nullptr, nullptr, 16384, 4096, 1024);
    gemm_k<3><<<dim3(128, 8), blk, 0, stream>>>(H1, W2T, b2, d_out, Obuf, x, 16384, 1024, 4096);
}

// Round 4
// 720.498 us; speedup vs baseline: 1.0410x; 1.0410x over previous
//
#include <hip/hip_runtime.h>
#include <hip/hip_bf16.h>
#include <cmath>

typedef __bf16 bf16_t;
typedef __bf16 bf16x8 __attribute__((ext_vector_type(8)));
typedef __bf16 bf16x4 __attribute__((ext_vector_type(4)));
typedef float f32x4 __attribute__((ext_vector_type(4)));

#define LATENT 1024
#define HEADS 16
#define HD 64
#define TX 4096
#define TXF 256
#define SCALE_ATTN 0.125f

static __device__ __forceinline__ float b2f(bf16_t b) { return (float)b; }
static __device__ __forceinline__ bf16_t f2b(float f) { return (bf16_t)f; }

// async global->LDS, 16B per lane; LDS dest = wave-uniform base + lane*16
static __device__ __forceinline__ void glds16(const bf16_t* g, bf16_t* l) {
    __builtin_amdgcn_global_load_lds(
        (const __attribute__((address_space(1))) void*)g,
        (__attribute__((address_space(3))) void*)l, 16, 0, 0);
}

// ---------------- f32 -> bf16 convert (vectorized, grid-stride) ----------
__global__ __launch_bounds__(256) void cvt_k(const float* __restrict__ in,
                                             bf16_t* __restrict__ out, long n4) {
    long i = (long)blockIdx.x * 256 + threadIdx.x;
    long stride = (long)gridDim.x * 256;
    for (; i < n4; i += stride) {
        float4 v = ((const float4*)in)[i];
        bf16x4 o;
        o[0] = f2b(v.x); o[1] = f2b(v.y); o[2] = f2b(v.z); o[3] = f2b(v.w);
        *(bf16x4*)&out[i * 4] = o;
    }
}

// ------------- transpose+convert: in f32 [R][C] -> out bf16 [C][R] -------
__global__ __launch_bounds__(256) void tr_k(const float* __restrict__ in,
                                            bf16_t* __restrict__ out,
                                            int R, int C) {
    __shared__ float t[32][33];
    int bx = blockIdx.x, by = blockIdx.y;
    int x = threadIdx.x & 31, y0 = threadIdx.x >> 5;  // 32 x 8
    for (int i = 0; i < 32; i += 8)
        t[y0 + i][x] = in[(long)(by * 32 + y0 + i) * C + bx * 32 + x];
    __syncthreads();
    for (int i = 0; i < 32; i += 8)
        out[(long)(bx * 32 + y0 + i) * R + by * 32 + x] = f2b(t[x][y0 + i]);
}

// ---------------- GEMM: C[M,N] = A[M,K] @ Bt[N,K]^T + bias(f32) ----------
// EPI: 0 = bf16 store, 2 = exact-GELU -> bf16,
//      3 = + resb16(bf16) + resf32(f32) -> F32 store (final output)
template <int EPI>
__global__ __launch_bounds__(256, 2) void gemm_k(
    const bf16_t* __restrict__ A, const bf16_t* __restrict__ Bt,
    const float* __restrict__ bias, void* __restrict__ C,
    const bf16_t* __restrict__ resb16, const float* __restrict__ resf32,
    int M, int N, int K) {
    // 128x128 tile, BK=32, 4 waves 2x2, each wave 4x4 of 16x16x32 MFMA.
    // Staging via global_load_lds w16: LDS slot is forced linear (tid*16),
    // so the XOR swizzle is applied on the SOURCE chunk index instead:
    //   slot s of row r holds chunk s ^ ((r>>1)&3)  (same image as r3).
    __shared__ __align__(16) bf16_t As[128 * 32];
    __shared__ __align__(16) bf16_t Bs[128 * 32];
    int tid = threadIdx.x;
    int lane = tid & 63, wid = tid >> 6;
    int quad = lane >> 4, l16 = lane & 15;
    int wm = wid >> 1, wn = wid & 1;
    int srow = tid >> 2;                       // 0..63
    int schunk = (tid & 3) ^ ((tid >> 3) & 3); // source-side swizzle

    f32x4 acc[4][4] = {};
    long bm = blockIdx.x, bn = blockIdx.y;
    const bf16_t* Ab = A + (bm * 128 + srow) * (long)K + schunk * 8;
    const bf16_t* Bb = Bt + (bn * 128 + srow) * (long)K + schunk * 8;
    bf16_t* AsW0 = (bf16_t*)((char*)As + wid * 1024);
    bf16_t* AsW1 = (bf16_t*)((char*)As + 4096 + wid * 1024);
    bf16_t* BsW0 = (bf16_t*)((char*)Bs + wid * 1024);
    bf16_t* BsW1 = (bf16_t*)((char*)Bs + 4096 + wid * 1024);

    for (int k0 = 0; k0 < K; k0 += 32) {
        __syncthreads();  // previous compute done reading LDS
        glds16(Ab + k0, AsW0);
        glds16(Ab + 64 * (long)K + k0, AsW1);
        glds16(Bb + k0, BsW0);
        glds16(Bb + 64 * (long)K + k0, BsW1);
        __syncthreads();  // drains vmcnt -> LDS ready
        bf16x8 af[4], bfr[4];
#pragma unroll
        for (int mi = 0; mi < 4; mi++) {
            int r = wm * 64 + mi * 16 + l16;
            af[mi] = *(const bf16x8*)&As[r * 32 + (quad ^ ((r >> 1) & 3)) * 8];
        }
#pragma unroll
        for (int ni = 0; ni < 4; ni++) {
            int r = wn * 64 + ni * 16 + l16;
            bfr[ni] = *(const bf16x8*)&Bs[r * 32 + (quad ^ ((r >> 1) & 3)) * 8];
        }
#pragma unroll
        for (int mi = 0; mi < 4; mi++)
#pragma unroll
            for (int ni = 0; ni < 4; ni++)
                acc[mi][ni] = __builtin_amdgcn_mfma_f32_16x16x32_bf16(
                    af[mi], bfr[ni], acc[mi][ni], 0, 0, 0);
    }

    // C/D layout: col = lane&15, row = quad*4 + reg (verified m89/m91)
    int colb = (int)bn * 128 + wn * 64;
    float bvv[4];
#pragma unroll
    for (int ni = 0; ni < 4; ni++) bvv[ni] = bias[colb + ni * 16 + l16];
#pragma unroll
    for (int mi = 0; mi < 4; mi++) {
        long grow = bm * 128 + wm * 64 + mi * 16 + quad * 4;
#pragma unroll
        for (int r = 0; r < 4; r++) {
            long ro = (grow + r) * (long)N;
#pragma unroll
            for (int ni = 0; ni < 4; ni++) {
                long idx = ro + colb + ni * 16 + l16;
                float v = acc[mi][ni][r] + bvv[ni];
                if (EPI == 0) {
                    ((bf16_t*)C)[idx] = f2b(v);
                } else if (EPI == 2) {
                    ((bf16_t*)C)[idx] =
                        f2b(0.5f * v * (1.0f + erff(v * 0.70710678118f)));
                } else {
                    // final: ffn + attn_out(bf16) + x(f32), stored f32
                    ((float*)C)[idx] = v + b2f(resb16[idx]) + resf32[idx];
                }
            }
        }
    }
}

// ---------------- fused attention (all-bf16 internal buffers) ------------
// Q[16384,1024], K/V[1024,1024] laid out (b*T + t, h*64 + d).
// Block: 64 q-rows of one (b,h). LDS 64KB: Ks swizzled [256][64] (later
// aliased by Ps [64][256]); Vt transposed swizzled [64 d][256 kk].
__global__ __launch_bounds__(256, 2) void attn_k(const bf16_t* __restrict__ Q,
                                                 const bf16_t* __restrict__ Kb,
                                                 const bf16_t* __restrict__ Vb,
                                                 bf16_t* __restrict__ Ob) {
    __shared__ __align__(16) bf16_t SM[32768];
    bf16_t* Ks = SM;
    bf16_t* Vt = SM + 16384;
    int tid = threadIdx.x;
    int lane = tid & 63, w = tid >> 6;
    int quad = lane >> 4, l16 = lane & 15;
    int qt = blockIdx.x & 63;
    int bh = blockIdx.x >> 6;
    int b = bh >> 4, h = bh & 15;

    {  // stage K (natural, swizzled) + V (transposed, swizzled); row = tid
        const uint4* ks = (const uint4*)(Kb + ((long)(b * TXF + tid) * LATENT + h * HD));
#pragma unroll
        for (int cc = 0; cc < 8; cc++)
            *(uint4*)&Ks[tid * 64 + ((cc ^ (tid & 7)) * 8)] = ks[cc];
        const uint4* vs = (const uint4*)(Vb + ((long)(b * TXF + tid) * LATENT + h * HD));
#pragma unroll
        for (int cc = 0; cc < 8; cc++) {
            uint4 v = vs[cc];
            const bf16_t* e = (const bf16_t*)&v;
#pragma unroll
            for (int j = 0; j < 8; j++) {
                int d = cc * 8 + j;
                Vt[d * 256 + (((tid >> 3) ^ (d & 7)) * 8) + (tid & 7)] = e[j];
            }
        }
    }
    // Q A-fragments from global (read-once): A[m=lane&15][k=quad*8+j]
    long qrow = (long)(b * TX + qt * 64 + w * 16 + l16) * LATENT + h * HD;
    bf16x8 aq0 = *(const bf16x8*)(Q + qrow + quad * 8);
    bf16x8 aq1 = *(const bf16x8*)(Q + qrow + 32 + quad * 8);
    __syncthreads();

    // scores: wave w owns q-rows [w*16, w*16+16), all 256 cols
    f32x4 sacc[16] = {};
#pragma unroll
    for (int ni = 0; ni < 16; ni++) {
        int kr = ni * 16 + l16;
        bf16x8 b0 = *(const bf16x8*)&Ks[kr * 64 + ((quad ^ (kr & 7)) * 8)];
        bf16x8 b1 = *(const bf16x8*)&Ks[kr * 64 + (((4 + quad) ^ (kr & 7)) * 8)];
        sacc[ni] = __builtin_amdgcn_mfma_f32_16x16x32_bf16(aq0, b0, sacc[ni], 0, 0, 0);
        sacc[ni] = __builtin_amdgcn_mfma_f32_16x16x32_bf16(aq1, b1, sacc[ni], 0, 0, 0);
    }
    // softmax per row (row = quad*4 + r); 16-lane butterfly stays in quad
#pragma unroll
    for (int r = 0; r < 4; r++) {
        float m = -3e38f;
#pragma unroll
        for (int ni = 0; ni < 16; ni++) m = fmaxf(m, sacc[ni][r]);
#pragma unroll
        for (int off = 1; off < 16; off <<= 1) m = fmaxf(m, __shfl_xor(m, off, 64));
        float s = 0.f;
#pragma unroll
        for (int ni = 0; ni < 16; ni++) {
            float p = __expf((sacc[ni][r] - m) * SCALE_ATTN);
            sacc[ni][r] = p;
            s += p;
        }
#pragma unroll
        for (int off = 1; off < 16; off <<= 1) s += __shfl_xor(s, off, 64);
        float inv = 1.0f / s;
#pragma unroll
        for (int ni = 0; ni < 16; ni++) sacc[ni][r] *= inv;
    }
    __syncthreads();  // all waves done reading Ks before Ps overwrites it

    bf16_t* Ps = SM;  // alias over Ks
#pragma unroll
    for (int r = 0; r < 4; r++) {
        int row = w * 16 + quad * 4 + r;
#pragma unroll
        for (int ni = 0; ni < 16; ni++) {
            int col = ni * 16 + l16;
            Ps[row * 256 + (((col >> 3) ^ (row & 7)) * 8) + (col & 7)] =
                f2b(sacc[ni][r]);
        }
    }
    __syncthreads();

    // PV: O[64 q][64 d]; wave w rows [w*16, w*16+16)
    f32x4 oacc[4] = {};
#pragma unroll
    for (int s = 0; s < 8; s++) {
        int prow = w * 16 + l16;
        bf16x8 ap = *(const bf16x8*)&Ps[prow * 256 + (((s * 4 + quad) ^ (prow & 7)) * 8)];
#pragma unroll
        for (int ni = 0; ni < 4; ni++) {
            int vr = ni * 16 + l16;
            bf16x8 bv = *(const bf16x8*)&Vt[vr * 256 + (((s * 4 + quad) ^ (vr & 7)) * 8)];
            oacc[ni] = __builtin_amdgcn_mfma_f32_16x16x32_bf16(ap, bv, oacc[ni], 0, 0, 0);
        }
    }
#pragma unroll
    for (int r = 0; r < 4; r++) {
        long orow = (long)(b * TX + qt * 64 + w * 16 + quad * 4 + r) * LATENT + h * HD;
#pragma unroll
        for (int ni = 0; ni < 4; ni++)
            Ob[orow + ni * 16 + l16] = f2b(oacc[ni][r]);
    }
}

// ------- LayerNorm: bf16 in, f32 gamma/beta (raw inputs), bf16 out -------
__global__ __launch_bounds__(256) void ln_k(const bf16_t* __restrict__ O,
                                            const float* __restrict__ g,
                                            const float* __restrict__ bb,
                                            bf16_t* __restrict__ H) {
    long row = blockIdx.x;
    int c = threadIdx.x * 4;
    bf16x4 v = *(const bf16x4*)(O + row * LATENT + c);
    float vv[4] = {b2f(v[0]), b2f(v[1]), b2f(v[2]), b2f(v[3])};
    float s = vv[0] + vv[1] + vv[2] + vv[3];
    float s2 = vv[0] * vv[0] + vv[1] * vv[1] + vv[2] * vv[2] + vv[3] * vv[3];
#pragma unroll
    for (int off = 1; off < 64; off <<= 1) {
        s += __shfl_xor(s, off, 64);
        s2 += __shfl_xor(s2, off, 64);
    }
    __shared__ float red[8];
    int lane = threadIdx.x & 63, w = threadIdx.x >> 6;
    if (lane == 0) { red[w] = s; red[w + 4] = s2; }
    __syncthreads();
    s = red[0] + red[1] + red[2] + red[3];
    s2 = red[4] + red[5] + red[6] + red[7];
    float mu = s * (1.0f / 1024.0f);
    float var = s2 * (1.0f / 1024.0f) - mu * mu;
    float rstd = rsqrtf(var + 1e-5f);
    bf16_t* out = H + row * LATENT + c;
#pragma unroll
    for (int j = 0; j < 4; j++)
        out[j] = f2b((vv[j] - mu) * rstd * g[c + j] + bb[c + j]);
}

// ---------------- launch ----------------
extern "C" void kernel_launch(void* const* d_in, const int* in_sizes, int n_in,
                              void* d_out, int out_size, void* d_ws,
                              size_t ws_size, hipStream_t stream) {
    // Inputs are FLOAT32; output buffer is FLOAT32 (reference output dtype).
    const float* x = (const float*)d_in[0];
    const float* xf = (const float*)d_in[1];
    const float* Wq = (const float*)d_in[2];
    const float* bq = (const float*)d_in[3];
    const float* Wk = (const float*)d_in[4];
    const float* bk = (const float*)d_in[5];
    const float* Wv = (const float*)d_in[6];
    const float* bv = (const float*)d_in[7];
    const float* Wo = (const float*)d_in[8];
    const float* bo = (const float*)d_in[9];
    const float* lng = (const float*)d_in[10];
    const float* lnb = (const float*)d_in[11];
    const float* W1 = (const float*)d_in[12];
    const float* b1 = (const float*)d_in[13];
    const float* W2 = (const float*)d_in[14];
    const float* b2 = (const float*)d_in[15];

    char* ws = (char*)d_ws;
    size_t off = 0;
    auto alloc = [&](size_t bytes) {
        void* p = ws + off;
        off += (bytes + 255) & ~(size_t)255;
        return p;
    };
    // persistent region (~87 MB)
    bf16_t* WqT = (bf16_t*)alloc((size_t)1024 * 1024 * 2);
    bf16_t* WkT = (bf16_t*)alloc((size_t)1024 * 768 * 2);
    bf16_t* WvT = (bf16_t*)alloc((size_t)1024 * 768 * 2);
    bf16_t* WoT = (bf16_t*)alloc((size_t)1024 * 1024 * 2);
    bf16_t* W1T = (bf16_t*)alloc((size_t)4096 * 1024 * 2);
    bf16_t* W2T = (bf16_t*)alloc((size_t)1024 * 4096 * 2);
    bf16_t* Obuf = (bf16_t*)alloc((size_t)16384 * 1024 * 2);  // attn proj out
    bf16_t* Hbuf = (bf16_t*)alloc((size_t)16384 * 1024 * 2);  // LN out
    // transient region (dead before FFN) — H1 aliases it (total ~215 MB)
    size_t transient0 = off;
    bf16_t* xc = (bf16_t*)alloc((size_t)16384 * 1024 * 2);
    bf16_t* xfc = (bf16_t*)alloc((size_t)1024 * 768 * 2);
    bf16_t* Qbuf = (bf16_t*)alloc((size_t)16384 * 1024 * 2);
    bf16_t* Kbuf = (bf16_t*)alloc((size_t)1024 * 1024 * 2);
    bf16_t* Vbuf = (bf16_t*)alloc((size_t)1024 * 1024 * 2);
    bf16_t* Abuf = (bf16_t*)alloc((size_t)16384 * 1024 * 2);
    bf16_t* H1 = (bf16_t*)(ws + transient0);  // 128 MB over dead transients

    dim3 blk(256);
    // input converts f32 -> bf16
    cvt_k<<<dim3(4096), blk, 0, stream>>>(x, xc, (long)16384 * 1024 / 4);
    cvt_k<<<dim3(768), blk, 0, stream>>>(xf, xfc, (long)1024 * 768 / 4);
    // weight transposes (+convert): grid (C/32, R/32)
    tr_k<<<dim3(32, 32), blk, 0, stream>>>(Wq, WqT, 1024, 1024);
    tr_k<<<dim3(32, 24), blk, 0, stream>>>(Wk, WkT, 768, 1024);
    tr_k<<<dim3(32, 24), blk, 0, stream>>>(Wv, WvT, 768, 1024);
    tr_k<<<dim3(32, 32), blk, 0, stream>>>(Wo, WoT, 1024, 1024);
    tr_k<<<dim3(128, 32), blk, 0, stream>>>(W1, W1T, 1024, 4096);
    tr_k<<<dim3(32, 128), blk, 0, stream>>>(W2, W2T, 4096, 1024);

    // projections
    gemm_k<0><<<dim3(128, 8), blk, 0, stream>>>(xc, WqT, bq, Qbuf, nullptr, nullptr, 16384, 1024, 1024);
    gemm_k<0><<<dim3(8, 8), blk, 0, stream>>>(xfc, WkT, bk, Kbuf, nullptr, nullptr, 1024, 1024, 768);
    gemm_k<0><<<dim3(8, 8), blk, 0, stream>>>(xfc, WvT, bv, Vbuf, nullptr, nullptr, 1024, 1024, 768);
    // attention
    attn_k<<<dim3(4096), blk, 0, stream>>>(Qbuf, Kbuf, Vbuf, Abuf);
    // output projection
    gemm_k<0><<<dim3(128, 8), blk, 0, stream>>>(Abuf, WoT, bo, Obuf, nullptr, nullptr, 16384, 1024, 1024);
    // layernorm
    ln_k<<<dim3(16384), blk, 0, stream>>>(Obuf, lng, lnb, Hbuf);
    // FFN
    gemm_k<2><<<dim3(128, 32), blk, 0, stream>>>(Hbuf, W1T, b1, H1, nullptr, nullptr, 16384, 4096, 1024);
    gemm_k<3><<<dim3(128, 8), blk, 0, stream>>>(H1, W2T, b2, d_out, Obuf, x, 16384, 1024, 4096);
}

// Round 5
// 666.436 us; speedup vs baseline: 1.1254x; 1.0811x over previous
//
#include <hip/hip_runtime.h>
#include <hip/hip_bf16.h>
#include <cmath>

typedef __bf16 bf16_t;
typedef __bf16 bf16x8 __attribute__((ext_vector_type(8)));
typedef __bf16 bf16x4 __attribute__((ext_vector_type(4)));
typedef float f32x4 __attribute__((ext_vector_type(4)));

#define LATENT 1024
#define HEADS 16
#define HD 64
#define TX 4096
#define TXF 256
#define SCALE_ATTN 0.125f

static __device__ __forceinline__ float b2f(bf16_t b) { return (float)b; }
static __device__ __forceinline__ bf16_t f2b(float f) { return (bf16_t)f; }

// async global->LDS, 16B per lane; LDS dest = wave-uniform base + lane*16
static __device__ __forceinline__ void glds16(const bf16_t* g, bf16_t* l) {
    __builtin_amdgcn_global_load_lds(
        (const __attribute__((address_space(1))) void*)g,
        (__attribute__((address_space(3))) void*)l, 16, 0, 0);
}

// ---------------- f32 -> bf16 convert (vectorized, grid-stride) ----------
__global__ __launch_bounds__(256) void cvt_k(const float* __restrict__ in,
                                             bf16_t* __restrict__ out, long n4) {
    long i = (long)blockIdx.x * 256 + threadIdx.x;
    long stride = (long)gridDim.x * 256;
    for (; i < n4; i += stride) {
        float4 v = ((const float4*)in)[i];
        bf16x4 o;
        o[0] = f2b(v.x); o[1] = f2b(v.y); o[2] = f2b(v.z); o[3] = f2b(v.w);
        *(bf16x4*)&out[i * 4] = o;
    }
}

// ------------- transpose+convert: in f32 [R][C] -> out bf16 [C][R] -------
__global__ __launch_bounds__(256) void tr_k(const float* __restrict__ in,
                                            bf16_t* __restrict__ out,
                                            int R, int C) {
    __shared__ float t[32][33];
    int bx = blockIdx.x, by = blockIdx.y;
    int x = threadIdx.x & 31, y0 = threadIdx.x >> 5;  // 32 x 8
    for (int i = 0; i < 32; i += 8)
        t[y0 + i][x] = in[(long)(by * 32 + y0 + i) * C + bx * 32 + x];
    __syncthreads();
    for (int i = 0; i < 32; i += 8)
        out[(long)(bx * 32 + y0 + i) * R + by * 32 + x] = f2b(t[x][y0 + i]);
}

// ---------------- GEMM: C[M,N] = A[M,K] @ Bt[N,K]^T + bias(f32) ----------
// EPI: 0 = bf16 store, 2 = exact-GELU -> bf16,
//      3 = + resb16(bf16) + resf32(f32) -> F32 store (final output)
template <int EPI>
__global__ __launch_bounds__(256, 2) void gemm_k(
    const bf16_t* __restrict__ A, const bf16_t* __restrict__ Bt,
    const float* __restrict__ bias, void* __restrict__ C,
    const bf16_t* __restrict__ resb16, const float* __restrict__ resf32,
    int M, int N, int K) {
    // 128x128 tile, BK=64 (32 MFMA/wave per barrier), 4 waves 2x2,
    // each wave 4x4 of 16x16x32 MFMA, 2 k-steps per tile.
    // Staging via global_load_lds w16 (linear slots); XOR swizzle applied on
    // the SOURCE chunk: slot s of row r holds chunk s ^ (r&7).
    __shared__ __align__(16) bf16_t As[128 * 64];
    __shared__ __align__(16) bf16_t Bs[128 * 64];
    int tid = threadIdx.x;
    int lane = tid & 63, wid = tid >> 6;
    int quad = lane >> 4, l16 = lane & 15;
    int wm = wid >> 1, wn = wid & 1;
    // transfer t covers rows t*32 + wid*8 + (lane>>3); chunk (lane&7)^(lane>>3)
    int srow0 = wid * 8 + (lane >> 3);
    int schunk = (lane & 7) ^ (lane >> 3);

    f32x4 acc[4][4] = {};
    long bm = blockIdx.x, bn = blockIdx.y;
    const bf16_t* Ab = A + (bm * 128 + srow0) * (long)K + schunk * 8;
    const bf16_t* Bb = Bt + (bn * 128 + srow0) * (long)K + schunk * 8;
    bf16_t* AsD = As + wid * 512;  // +t*2048; HW adds lane*16B (=lane*8 elems)
    bf16_t* BsD = Bs + wid * 512;

    for (int k0 = 0; k0 < K; k0 += 64) {
        __syncthreads();  // previous compute done reading LDS
#pragma unroll
        for (int t = 0; t < 4; t++) {
            glds16(Ab + k0 + (long)t * 32 * K, AsD + t * 2048);
            glds16(Bb + k0 + (long)t * 32 * K, BsD + t * 2048);
        }
        __syncthreads();  // drains vmcnt -> LDS ready
#pragma unroll
        for (int s = 0; s < 2; s++) {
            bf16x8 af[4], bfr[4];
#pragma unroll
            for (int mi = 0; mi < 4; mi++) {
                int r = wm * 64 + mi * 16 + l16;
                af[mi] = *(const bf16x8*)&As[r * 64 + (((s * 4 + quad) ^ (r & 7)) * 8)];
            }
#pragma unroll
            for (int ni = 0; ni < 4; ni++) {
                int r = wn * 64 + ni * 16 + l16;
                bfr[ni] = *(const bf16x8*)&Bs[r * 64 + (((s * 4 + quad) ^ (r & 7)) * 8)];
            }
#pragma unroll
            for (int mi = 0; mi < 4; mi++)
#pragma unroll
                for (int ni = 0; ni < 4; ni++)
                    acc[mi][ni] = __builtin_amdgcn_mfma_f32_16x16x32_bf16(
                        af[mi], bfr[ni], acc[mi][ni], 0, 0, 0);
        }
    }

    // C/D layout: col = lane&15, row = quad*4 + reg (verified m89/m91)
    int colb = (int)bn * 128 + wn * 64;
    float bvv[4];
#pragma unroll
    for (int ni = 0; ni < 4; ni++) bvv[ni] = bias[colb + ni * 16 + l16];
#pragma unroll
    for (int mi = 0; mi < 4; mi++) {
        long grow = bm * 128 + wm * 64 + mi * 16 + quad * 4;
#pragma unroll
        for (int r = 0; r < 4; r++) {
            long ro = (grow + r) * (long)N;
#pragma unroll
            for (int ni = 0; ni < 4; ni++) {
                long idx = ro + colb + ni * 16 + l16;
                float v = acc[mi][ni][r] + bvv[ni];
                if (EPI == 0) {
                    ((bf16_t*)C)[idx] = f2b(v);
                } else if (EPI == 2) {
                    ((bf16_t*)C)[idx] =
                        f2b(0.5f * v * (1.0f + erff(v * 0.70710678118f)));
                } else {
                    // final: ffn + attn_out(bf16) + x(f32), stored f32
                    ((float*)C)[idx] = v + b2f(resb16[idx]) + resf32[idx];
                }
            }
        }
    }
}

// ---------------- fused attention (all-bf16 internal buffers) ------------
// Q[16384,1024], K/V[1024,1024] laid out (b*T + t, h*64 + d).
// Block: 64 q-rows of one (b,h). LDS 64KB: Ks swizzled [256][64] (later
// aliased by Ps [64][256]); Vt transposed swizzled [64 d][256 kk].
__global__ __launch_bounds__(256, 2) void attn_k(const bf16_t* __restrict__ Q,
                                                 const bf16_t* __restrict__ Kb,
                                                 const bf16_t* __restrict__ Vb,
                                                 bf16_t* __restrict__ Ob) {
    __shared__ __align__(16) bf16_t SM[32768];
    bf16_t* Ks = SM;
    bf16_t* Vt = SM + 16384;
    int tid = threadIdx.x;
    int lane = tid & 63, w = tid >> 6;
    int quad = lane >> 4, l16 = lane & 15;
    int qt = blockIdx.x & 63;
    int bh = blockIdx.x >> 6;
    int b = bh >> 4, h = bh & 15;

    {  // stage K (natural, swizzled) + V (transposed, swizzled); row = tid
        const uint4* ks = (const uint4*)(Kb + ((long)(b * TXF + tid) * LATENT + h * HD));
#pragma unroll
        for (int cc = 0; cc < 8; cc++)
            *(uint4*)&Ks[tid * 64 + ((cc ^ (tid & 7)) * 8)] = ks[cc];
        const uint4* vs = (const uint4*)(Vb + ((long)(b * TXF + tid) * LATENT + h * HD));
#pragma unroll
        for (int cc = 0; cc < 8; cc++) {
            uint4 v = vs[cc];
            const bf16_t* e = (const bf16_t*)&v;
#pragma unroll
            for (int j = 0; j < 8; j++) {
                int d = cc * 8 + j;
                Vt[d * 256 + (((tid >> 3) ^ (d & 7)) * 8) + (tid & 7)] = e[j];
            }
        }
    }
    // Q A-fragments from global (read-once): A[m=lane&15][k=quad*8+j]
    long qrow = (long)(b * TX + qt * 64 + w * 16 + l16) * LATENT + h * HD;
    bf16x8 aq0 = *(const bf16x8*)(Q + qrow + quad * 8);
    bf16x8 aq1 = *(const bf16x8*)(Q + qrow + 32 + quad * 8);
    __syncthreads();

    // scores: wave w owns q-rows [w*16, w*16+16), all 256 cols
    f32x4 sacc[16] = {};
#pragma unroll
    for (int ni = 0; ni < 16; ni++) {
        int kr = ni * 16 + l16;
        bf16x8 b0 = *(const bf16x8*)&Ks[kr * 64 + ((quad ^ (kr & 7)) * 8)];
        bf16x8 b1 = *(const bf16x8*)&Ks[kr * 64 + (((4 + quad) ^ (kr & 7)) * 8)];
        sacc[ni] = __builtin_amdgcn_mfma_f32_16x16x32_bf16(aq0, b0, sacc[ni], 0, 0, 0);
        sacc[ni] = __builtin_amdgcn_mfma_f32_16x16x32_bf16(aq1, b1, sacc[ni], 0, 0, 0);
    }
    // softmax per row (row = quad*4 + r); 16-lane butterfly stays in quad
#pragma unroll
    for (int r = 0; r < 4; r++) {
        float m = -3e38f;
#pragma unroll
        for (int ni = 0; ni < 16; ni++) m = fmaxf(m, sacc[ni][r]);
#pragma unroll
        for (int off = 1; off < 16; off <<= 1) m = fmaxf(m, __shfl_xor(m, off, 64));
        float s = 0.f;
#pragma unroll
        for (int ni = 0; ni < 16; ni++) {
            float p = __expf((sacc[ni][r] - m) * SCALE_ATTN);
            sacc[ni][r] = p;
            s += p;
        }
#pragma unroll
        for (int off = 1; off < 16; off <<= 1) s += __shfl_xor(s, off, 64);
        float inv = 1.0f / s;
#pragma unroll
        for (int ni = 0; ni < 16; ni++) sacc[ni][r] *= inv;
    }
    __syncthreads();  // all waves done reading Ks before Ps overwrites it

    bf16_t* Ps = SM;  // alias over Ks
#pragma unroll
    for (int r = 0; r < 4; r++) {
        int row = w * 16 + quad * 4 + r;
#pragma unroll
        for (int ni = 0; ni < 16; ni++) {
            int col = ni * 16 + l16;
            Ps[row * 256 + (((col >> 3) ^ (row & 7)) * 8) + (col & 7)] =
                f2b(sacc[ni][r]);
        }
    }
    __syncthreads();

    // PV: O[64 q][64 d]; wave w rows [w*16, w*16+16)
    f32x4 oacc[4] = {};
#pragma unroll
    for (int s = 0; s < 8; s++) {
        int prow = w * 16 + l16;
        bf16x8 ap = *(const bf16x8*)&Ps[prow * 256 + (((s * 4 + quad) ^ (prow & 7)) * 8)];
#pragma unroll
        for (int ni = 0; ni < 4; ni++) {
            int vr = ni * 16 + l16;
            bf16x8 bv = *(const bf16x8*)&Vt[vr * 256 + (((s * 4 + quad) ^ (vr & 7)) * 8)];
            oacc[ni] = __builtin_amdgcn_mfma_f32_16x16x32_bf16(ap, bv, oacc[ni], 0, 0, 0);
        }
    }
#pragma unroll
    for (int r = 0; r < 4; r++) {
        long orow = (long)(b * TX + qt * 64 + w * 16 + quad * 4 + r) * LATENT + h * HD;
#pragma unroll
        for (int ni = 0; ni < 4; ni++)
            Ob[orow + ni * 16 + l16] = f2b(oacc[ni][r]);
    }
}

// ------- LayerNorm: bf16 in, f32 gamma/beta (raw inputs), bf16 out -------
__global__ __launch_bounds__(256) void ln_k(const bf16_t* __restrict__ O,
                                            const float* __restrict__ g,
                                            const float* __restrict__ bb,
                                            bf16_t* __restrict__ H) {
    long row = blockIdx.x;
    int c = threadIdx.x * 4;
    bf16x4 v = *(const bf16x4*)(O + row * LATENT + c);
    float vv[4] = {b2f(v[0]), b2f(v[1]), b2f(v[2]), b2f(v[3])};
    float s = vv[0] + vv[1] + vv[2] + vv[3];
    float s2 = vv[0] * vv[0] + vv[1] * vv[1] + vv[2] * vv[2] + vv[3] * vv[3];
#pragma unroll
    for (int off = 1; off < 64; off <<= 1) {
        s += __shfl_xor(s, off, 64);
        s2 += __shfl_xor(s2, off, 64);
    }
    __shared__ float red[8];
    int lane = threadIdx.x & 63, w = threadIdx.x >> 6;
    if (lane == 0) { red[w] = s; red[w + 4] = s2; }
    __syncthreads();
    s = red[0] + red[1] + red[2] + red[3];
    s2 = red[4] + red[5] + red[6] + red[7];
    float mu = s * (1.0f / 1024.0f);
    float var = s2 * (1.0f / 1024.0f) - mu * mu;
    float rstd = rsqrtf(var + 1e-5f);
    bf16_t* out = H + row * LATENT + c;
#pragma unroll
    for (int j = 0; j < 4; j++)
        out[j] = f2b((vv[j] - mu) * rstd * g[c + j] + bb[c + j]);
}

// ---------------- launch ----------------
extern "C" void kernel_launch(void* const* d_in, const int* in_sizes, int n_in,
                              void* d_out, int out_size, void* d_ws,
                              size_t ws_size, hipStream_t stream) {
    // Inputs are FLOAT32; output buffer is FLOAT32 (reference output dtype).
    const float* x = (const float*)d_in[0];
    const float* xf = (const float*)d_in[1];
    const float* Wq = (const float*)d_in[2];
    const float* bq = (const float*)d_in[3];
    const float* Wk = (const float*)d_in[4];
    const float* bk = (const float*)d_in[5];
    const float* Wv = (const float*)d_in[6];
    const float* bv = (const float*)d_in[7];
    const float* Wo = (const float*)d_in[8];
    const float* bo = (const float*)d_in[9];
    const float* lng = (const float*)d_in[10];
    const float* lnb = (const float*)d_in[11];
    const float* W1 = (const float*)d_in[12];
    const float* b1 = (const float*)d_in[13];
    const float* W2 = (const float*)d_in[14];
    const float* b2 = (const float*)d_in[15];

    char* ws = (char*)d_ws;
    size_t off = 0;
    auto alloc = [&](size_t bytes) {
        void* p = ws + off;
        off += (bytes + 255) & ~(size_t)255;
        return p;
    };
    // persistent region (~87 MB)
    bf16_t* WqT = (bf16_t*)alloc((size_t)1024 * 1024 * 2);
    bf16_t* WkT = (bf16_t*)alloc((size_t)1024 * 768 * 2);
    bf16_t* WvT = (bf16_t*)alloc((size_t)1024 * 768 * 2);
    bf16_t* WoT = (bf16_t*)alloc((size_t)1024 * 1024 * 2);
    bf16_t* W1T = (bf16_t*)alloc((size_t)4096 * 1024 * 2);
    bf16_t* W2T = (bf16_t*)alloc((size_t)1024 * 4096 * 2);
    bf16_t* Obuf = (bf16_t*)alloc((size_t)16384 * 1024 * 2);  // attn proj out
    bf16_t* Hbuf = (bf16_t*)alloc((size_t)16384 * 1024 * 2);  // LN out
    // transient region (dead before FFN) — H1 aliases it (total ~215 MB)
    size_t transient0 = off;
    bf16_t* xc = (bf16_t*)alloc((size_t)16384 * 1024 * 2);
    bf16_t* xfc = (bf16_t*)alloc((size_t)1024 * 768 * 2);
    bf16_t* Qbuf = (bf16_t*)alloc((size_t)16384 * 1024 * 2);
    bf16_t* Kbuf = (bf16_t*)alloc((size_t)1024 * 1024 * 2);
    bf16_t* Vbuf = (bf16_t*)alloc((size_t)1024 * 1024 * 2);
    bf16_t* Abuf = (bf16_t*)alloc((size_t)16384 * 1024 * 2);
    bf16_t* H1 = (bf16_t*)(ws + transient0);  // 128 MB over dead transients

    dim3 blk(256);
    // input converts f32 -> bf16
    cvt_k<<<dim3(4096), blk, 0, stream>>>(x, xc, (long)16384 * 1024 / 4);
    cvt_k<<<dim3(768), blk, 0, stream>>>(xf, xfc, (long)1024 * 768 / 4);
    // weight transposes (+convert): grid (C/32, R/32)
    tr_k<<<dim3(32, 32), blk, 0, stream>>>(Wq, WqT, 1024, 1024);
    tr_k<<<dim3(32, 24), blk, 0, stream>>>(Wk, WkT, 768, 1024);
    tr_k<<<dim3(32, 24), blk, 0, stream>>>(Wv, WvT, 768, 1024);
    tr_k<<<dim3(32, 32), blk, 0, stream>>>(Wo, WoT, 1024, 1024);
    tr_k<<<dim3(128, 32), blk, 0, stream>>>(W1, W1T, 1024, 4096);
    tr_k<<<dim3(32, 128), blk, 0, stream>>>(W2, W2T, 4096, 1024);

    // projections
    gemm_k<0><<<dim3(128, 8), blk, 0, stream>>>(xc, WqT, bq, Qbuf, nullptr, nullptr, 16384, 1024, 1024);
    gemm_k<0><<<dim3(8, 8), blk, 0, stream>>>(xfc, WkT, bk, Kbuf, nullptr, nullptr, 1024, 1024, 768);
    gemm_k<0><<<dim3(8, 8), blk, 0, stream>>>(xfc, WvT, bv, Vbuf, nullptr, nullptr, 1024, 1024, 768);
    // attention
    attn_k<<<dim3(4096), blk, 0, stream>>>(Qbuf, Kbuf, Vbuf, Abuf);
    // output projection
    gemm_k<0><<<dim3(128, 8), blk, 0, stream>>>(Abuf, WoT, bo, Obuf, nullptr, nullptr, 16384, 1024, 1024);
    // layernorm
    ln_k<<<dim3(16384), blk, 0, stream>>>(Obuf, lng, lnb, Hbuf);
    // FFN
    gemm_k<2><<<dim3(128, 32), blk, 0, stream>>>(Hbuf, W1T, b1, H1, nullptr, nullptr, 16384, 4096, 1024);
    gemm_k<3><<<dim3(128, 8), blk, 0, stream>>>(H1, W2T, b2, d_out, Obuf, x, 16384, 1024, 4096);
}